// Round 6
// baseline (404.314 us; speedup 1.0000x reference)
//
#include <hip/hip_runtime.h>
#include <hip/hip_cooperative_groups.h>

namespace cg = cooperative_groups;

#define NQ   131072
#define PCNT 2048
#define NBIN 4096
#define QPT  4              /* queries per thread in main phase */
#define NCH  8              /* rep chunks in main phase */
#define RPC  (PCNT / NCH)   /* 256 reps per chunk */
#define NB   1024           /* mega-kernel blocks (4/CU co-resident) */

// ws layout (bytes)
#define HIST_OFF 0                         /* NBIN*4 = 16384 */
#define CTRL_OFF 16384                     /* 256 B  */
#define KEYS_OFF (16384 + 256)             /* NQ*4   */
#define CAND_OFF (KEYS_OFF + NQ * 4)       /* NQ*4   */
#define REPS_OFF (CAND_OFF + NQ * 4)       /* PCNT*16, 16B aligned */
#define PART_OFF (REPS_OFF + PCNT * 16)    /* NCH*NQ*4 */

// ctrl: [5]=curL [6]=curE [7]=cand cursor (M)

__device__ __forceinline__ float sumsq_nc(float x, float y, float z) {
#pragma clang fp contract(off)
  return x * x + y * y + z * z;
}

// ---------- cooperative mega-kernel: 2 dispatches total ----------
__global__ __launch_bounds__(256, 4) void k_mega(const float* __restrict__ q,
                                                 unsigned* __restrict__ keys,
                                                 unsigned* __restrict__ hist,
                                                 unsigned* __restrict__ ctrl,
                                                 unsigned* __restrict__ cand,
                                                 float4* __restrict__ reps,
                                                 float* __restrict__ part,
                                                 float* __restrict__ out) {
  cg::grid_group grid = cg::this_grid();
  __shared__ __align__(16) unsigned h[NBIN];   // hist / h2 / rep-stage (reused)
  __shared__ unsigned part_s[256];
  __shared__ unsigned h3[256];
  __shared__ unsigned sB1, sC1, sB2, sC2, sN2, sT, sCL, sK2;
  __shared__ unsigned tot, base, cur, totL, totE, curL, curE;
  int t = threadIdx.x;
  int bid = blockIdx.x;

  // ---- Phase A: keys + LDS hist + flush (128 active blocks; hist/ctrl
  //      pre-zeroed by the on-stream memset) ----
  if (bid < 128) {
    for (int j = t; j < NBIN; j += 256) h[j] = 0;
    __syncthreads();
    int st = bid * 256 + t;
#pragma unroll
    for (int l = 0; l < 4; ++l) {
      int i = st + l * 32768;
      float x = q[3 * i], y = q[3 * i + 1], z = q[3 * i + 2];
      float s = sumsq_nc(x, y, z);
      float d = sqrtf(s) - 0.5f;
      unsigned k = __float_as_uint(fabsf(d));  // nonneg float: bits monotone
      keys[i] = k;
      atomicAdd(&h[k >> 20], 1u);
    }
    __syncthreads();
    for (int j = t; j < NBIN; j += 256) {
      unsigned v = h[j];
      if (v) atomicAdd(&hist[j], v);
    }
  }
  grid.sync();  // hist complete

  // ---- Phase C: coarse scan (redundant/block) + compact candidates ----
  if (bid < 128) {
    if (t == 0) tot = 0;
    // coarse scan: bin B1 containing PCNT-th smallest, C1 = #below
    {
      unsigned s = 0;
      for (int j = 0; j < 16; ++j) s += hist[t * 16 + j];
      part_s[t] = s;
      __syncthreads();
      if (t == 0) {
        unsigned cum = 0; int c = 0;
        for (; c < 256; ++c) { if (cum + part_s[c] >= PCNT) break; cum += part_s[c]; }
        unsigned b = c * 16;
        for (;; ++b) { unsigned v = hist[b]; if (cum + v >= PCNT) break; cum += v; }
        sB1 = b; sC1 = cum;
      }
      __syncthreads();
    }
    unsigned B1 = sB1;
    int st = bid * 256 + t;
    unsigned kk[4]; unsigned n = 0;
#pragma unroll
    for (int l = 0; l < 4; ++l) { kk[l] = keys[st + l * 32768]; n += ((kk[l] >> 20) == B1); }
    if (n) atomicAdd(&tot, n);
    __syncthreads();
    if (t == 0) { base = atomicAdd(&ctrl[7], tot); cur = 0; }
    __syncthreads();
    int lane = t & 63;
#pragma unroll
    for (int l = 0; l < 4; ++l) {
      bool m = (kk[l] >> 20) == B1;
      unsigned long long mb = __ballot(m);
      unsigned wcnt = __popcll(mb);
      if (wcnt) {
        unsigned lb = 0;
        if (lane == 0) lb = atomicAdd(&cur, wcnt);
        lb = __shfl(lb, 0);
        if (m) cand[base + lb + __popcll(mb & ((1ull << lane) - 1ull))] = kk[l];
      }
    }
  }
  grid.sync();  // cand + ctrl[7] complete

  // ---- Phase D: exact select over cand (redundant/block) + rep build ----
  if (bid < 128) {
    for (int j = t; j < NBIN; j += 256) h[j] = 0;
    h3[t] = 0;
    if (t == 0) { totL = 0; totE = 0; }
    __syncthreads();
    unsigned M = ctrl[7];
    for (unsigned j = t; j < M; j += 256) atomicAdd(&h[(cand[j] >> 8) & 0xFFFu], 1u);
    __syncthreads();
    unsigned s = 0;
    for (int j = 0; j < 16; ++j) s += h[t * 16 + j];
    part_s[t] = s;
    __syncthreads();
    if (t == 0) {
      unsigned need = PCNT - sC1;
      unsigned cum = 0; int c = 0;
      for (; c < 256; ++c) { if (cum + part_s[c] >= need) break; cum += part_s[c]; }
      unsigned b = c * 16;
      for (;; ++b) { unsigned v = h[b]; if (cum + v >= need) break; cum += v; }
      sB2 = b; sC2 = cum; sN2 = need - cum;
    }
    __syncthreads();
    unsigned b2 = sB2;
    for (unsigned j = t; j < M; j += 256) {
      unsigned k = cand[j];
      if (((k >> 8) & 0xFFFu) == b2) atomicAdd(&h3[k & 0xFFu], 1u);
    }
    __syncthreads();
    if (t == 0) {
      unsigned need2 = sN2, cum = 0, b = 0;
      for (;; ++b) { unsigned v = h3[b]; if (cum + v >= need2) break; cum += v; }
      sT = (sB1 << 20) | (b2 << 8) | b;
      sCL = sC1 + sC2 + cum;
      sK2 = PCNT - sCL;
    }
    __syncthreads();
    unsigned T = sT, CL = sCL, K2 = sK2;
    int st = bid * 256 + t;
    unsigned kk[4]; unsigned nl = 0, ne = 0;
#pragma unroll
    for (int l = 0; l < 4; ++l) {
      kk[l] = keys[st + l * 32768];
      nl += (kk[l] < T); ne += (kk[l] == T);
    }
    if (nl) atomicAdd(&totL, nl);
    if (ne) atomicAdd(&totE, ne);
    __syncthreads();
    if (t == 0) { curL = atomicAdd(&ctrl[5], totL); curE = atomicAdd(&ctrl[6], totE); }
    __syncthreads();
    int lane = t & 63;
#pragma unroll
    for (int l = 0; l < 4; ++l) {
      int i = st + l * 32768;
      unsigned k = kk[l];
      bool lt = k < T, eq = k == T;
      unsigned long long ml = __ballot(lt), me = __ballot(eq);
      unsigned wl = __popcll(ml), we = __popcll(me);
      unsigned bl = 0, be = 0;
      if (wl) { if (lane == 0) bl = atomicAdd(&curL, wl); bl = __shfl(bl, 0); }
      if (we) { if (lane == 0) be = atomicAdd(&curE, we); be = __shfl(be, 0); }
      int pos = -1;
      if (lt) pos = (int)(bl + __popcll(ml & ((1ull << lane) - 1ull)));
      else if (eq) {
        unsigned e = be + __popcll(me & ((1ull << lane) - 1ull));
        if (e < K2) pos = (int)(CL + e);
      }
      if (pos >= 0) {
        float x = q[3 * i], y = q[3 * i + 1], z = q[3 * i + 2];
        reps[pos] = make_float4(x, y, z, sumsq_nc(x, y, z));
      }
    }
  }
  grid.sync();  // reps complete

  // ---- Phase E: main distance loop, all 1024 blocks ----
  {
    float4* lds = (float4*)h;  // reuse 16KB region (4KB needed)
    int c = bid & 7;
    int qb = bid >> 3;
    const float4* rp = reps + c * RPC;
    if (t < RPC) lds[t] = rp[t];
    int qbase = qb * (256 * QPT) + t;
    float qx[QPT], qy[QPT], qz[QPT], mn[QPT];
#pragma unroll
    for (int k = 0; k < QPT; ++k) {
      int i = qbase + k * 256;
      qx[k] = -2.0f * q[3 * i];
      qy[k] = -2.0f * q[3 * i + 1];
      qz[k] = -2.0f * q[3 * i + 2];
      mn[k] = 1e30f;
    }
    __syncthreads();
#pragma unroll 2
    for (int j = 0; j < RPC; j += 4) {
      float4 r0 = lds[j], r1 = lds[j + 1], r2 = lds[j + 2], r3 = lds[j + 3];
#pragma unroll
      for (int k = 0; k < QPT; ++k) {
        float t0 = fmaf(qx[k], r0.x, fmaf(qy[k], r0.y, fmaf(qz[k], r0.z, r0.w)));
        float t1 = fmaf(qx[k], r1.x, fmaf(qy[k], r1.y, fmaf(qz[k], r1.z, r1.w)));
        float t2 = fmaf(qx[k], r2.x, fmaf(qy[k], r2.y, fmaf(qz[k], r2.z, r2.w)));
        float t3 = fmaf(qx[k], r3.x, fmaf(qy[k], r3.y, fmaf(qz[k], r3.z, r3.w)));
        mn[k] = fminf(mn[k], fminf(t0, t1));  // v_min3_f32
        mn[k] = fminf(mn[k], fminf(t2, t3));
      }
    }
#pragma unroll
    for (int k = 0; k < QPT; ++k) part[c * NQ + qbase + k * 256] = mn[k];
  }
  grid.sync();  // part complete

  // ---- Phase F: reduce + epilogue (512 active blocks) ----
  if (bid < 512) {
    int i = bid * 256 + t;
    float m = part[i];
#pragma unroll
    for (int c = 1; c < NCH; ++c) m = fminf(m, part[c * NQ + i]);
    float x = q[3 * i], y = q[3 * i + 1], z = q[3 * i + 2];
    float s = sumsq_nc(x, y, z);
    float d = sqrtf(s) - 0.5f;
    float d2 = fmaxf(s + m, 0.0f);
    float nd = (d2 > 0.0f) ? sqrtf(d2) : 0.0f;
    float sg = (d > 0.0f) ? 1.0f : ((d < 0.0f) ? -1.0f : 0.0f);
    out[i] = fminf(nd * sg, d);
  }
}

// ---------- fallback path (round-5 multi-kernel, proven) ----------
__global__ __launch_bounds__(256) void k_keys(const float* __restrict__ q,
                                              unsigned* __restrict__ keys,
                                              unsigned* __restrict__ hist,
                                              unsigned* __restrict__ ctrl) {
  __shared__ unsigned h[NBIN];
  int t = threadIdx.x;
  for (int j = t; j < NBIN; j += 256) h[j] = 0;
  if (blockIdx.x == 0 && t >= 5 && t < 8) ctrl[t] = 0;
  __syncthreads();
  int base = blockIdx.x * 256 + t;
#pragma unroll
  for (int l = 0; l < 4; ++l) {
    int i = base + l * 32768;
    float x = q[3 * i], y = q[3 * i + 1], z = q[3 * i + 2];
    float s = sumsq_nc(x, y, z);
    float d = sqrtf(s) - 0.5f;
    unsigned k = __float_as_uint(fabsf(d));
    keys[i] = k;
    atomicAdd(&h[k >> 20], 1u);
  }
  __syncthreads();
  for (int j = t; j < NBIN; j += 256) {
    unsigned v = h[j];
    if (v) atomicAdd(&hist[j], v);
  }
}

__device__ __forceinline__ void coarse_scan(const unsigned* __restrict__ hist,
                                            unsigned* part, unsigned* pB1,
                                            unsigned* pC1) {
  int t = threadIdx.x;
  unsigned s = 0;
  for (int j = 0; j < 16; ++j) s += hist[t * 16 + j];
  part[t] = s;
  __syncthreads();
  if (t == 0) {
    unsigned cum = 0; int c = 0;
    for (; c < 256; ++c) { if (cum + part[c] >= PCNT) break; cum += part[c]; }
    unsigned b = c * 16;
    for (;; ++b) { unsigned v = hist[b]; if (cum + v >= PCNT) break; cum += v; }
    *pB1 = b; *pC1 = cum;
  }
  __syncthreads();
}

__global__ __launch_bounds__(256) void k_compact1(const unsigned* __restrict__ keys,
                                                  const unsigned* __restrict__ hist,
                                                  unsigned* __restrict__ ctrl,
                                                  unsigned* __restrict__ cand) {
  __shared__ unsigned part[256];
  __shared__ unsigned sB1, sC1;
  __shared__ unsigned tot, base, cur;
  int t = threadIdx.x;
  if (t == 0) tot = 0;
  coarse_scan(hist, part, &sB1, &sC1);
  unsigned B1 = sB1;
  int st = blockIdx.x * 256 + t;
  unsigned kk[4]; unsigned n = 0;
#pragma unroll
  for (int l = 0; l < 4; ++l) { kk[l] = keys[st + l * 32768]; n += ((kk[l] >> 20) == B1); }
  if (n) atomicAdd(&tot, n);
  __syncthreads();
  if (t == 0) { base = atomicAdd(&ctrl[7], tot); cur = 0; }
  __syncthreads();
  int lane = t & 63;
#pragma unroll
  for (int l = 0; l < 4; ++l) {
    bool m = (kk[l] >> 20) == B1;
    unsigned long long mb = __ballot(m);
    unsigned wcnt = __popcll(mb);
    if (wcnt) {
      unsigned lb = 0;
      if (lane == 0) lb = atomicAdd(&cur, wcnt);
      lb = __shfl(lb, 0);
      if (m) cand[base + lb + __popcll(mb & ((1ull << lane) - 1ull))] = kk[l];
    }
  }
}

__global__ __launch_bounds__(256) void k_repbuild(const float* __restrict__ q,
                                                  const unsigned* __restrict__ keys,
                                                  const unsigned* __restrict__ hist,
                                                  unsigned* __restrict__ ctrl,
                                                  const unsigned* __restrict__ cand,
                                                  float4* __restrict__ reps) {
  __shared__ unsigned part[256];
  __shared__ unsigned h2[NBIN];
  __shared__ unsigned h3[256];
  __shared__ unsigned sB1, sC1, sB2, sC2, sN2, sT, sCL, sK2;
  __shared__ unsigned totL, totE, curL, curE;
  int t = threadIdx.x;
  for (int j = t; j < NBIN; j += 256) h2[j] = 0;
  h3[t] = 0;
  if (t == 0) { totL = 0; totE = 0; }
  coarse_scan(hist, part, &sB1, &sC1);
  unsigned M = ctrl[7];
  for (unsigned j = t; j < M; j += 256) atomicAdd(&h2[(cand[j] >> 8) & 0xFFFu], 1u);
  __syncthreads();
  unsigned s = 0;
  for (int j = 0; j < 16; ++j) s += h2[t * 16 + j];
  part[t] = s;
  __syncthreads();
  if (t == 0) {
    unsigned need = PCNT - sC1;
    unsigned cum = 0; int c = 0;
    for (; c < 256; ++c) { if (cum + part[c] >= need) break; cum += part[c]; }
    unsigned b = c * 16;
    for (;; ++b) { unsigned v = h2[b]; if (cum + v >= need) break; cum += v; }
    sB2 = b; sC2 = cum; sN2 = need - cum;
  }
  __syncthreads();
  unsigned b2 = sB2;
  for (unsigned j = t; j < M; j += 256) {
    unsigned k = cand[j];
    if (((k >> 8) & 0xFFFu) == b2) atomicAdd(&h3[k & 0xFFu], 1u);
  }
  __syncthreads();
  if (t == 0) {
    unsigned need2 = sN2, cum = 0, b = 0;
    for (;; ++b) { unsigned v = h3[b]; if (cum + v >= need2) break; cum += v; }
    sT = (sB1 << 20) | (b2 << 8) | b;
    sCL = sC1 + sC2 + cum;
    sK2 = PCNT - sCL;
  }
  __syncthreads();
  unsigned T = sT, CL = sCL, K2 = sK2;
  int st = blockIdx.x * 256 + t;
  unsigned kk[4]; unsigned nl = 0, ne = 0;
#pragma unroll
  for (int l = 0; l < 4; ++l) {
    kk[l] = keys[st + l * 32768];
    nl += (kk[l] < T); ne += (kk[l] == T);
  }
  if (nl) atomicAdd(&totL, nl);
  if (ne) atomicAdd(&totE, ne);
  __syncthreads();
  if (t == 0) { curL = atomicAdd(&ctrl[5], totL); curE = atomicAdd(&ctrl[6], totE); }
  __syncthreads();
  int lane = t & 63;
#pragma unroll
  for (int l = 0; l < 4; ++l) {
    int i = st + l * 32768;
    unsigned k = kk[l];
    bool lt = k < T, eq = k == T;
    unsigned long long ml = __ballot(lt), me = __ballot(eq);
    unsigned wl = __popcll(ml), we = __popcll(me);
    unsigned bl = 0, be = 0;
    if (wl) { if (lane == 0) bl = atomicAdd(&curL, wl); bl = __shfl(bl, 0); }
    if (we) { if (lane == 0) be = atomicAdd(&curE, we); be = __shfl(be, 0); }
    int pos = -1;
    if (lt) pos = (int)(bl + __popcll(ml & ((1ull << lane) - 1ull)));
    else if (eq) {
      unsigned e = be + __popcll(me & ((1ull << lane) - 1ull));
      if (e < K2) pos = (int)(CL + e);
    }
    if (pos >= 0) {
      float x = q[3 * i], y = q[3 * i + 1], z = q[3 * i + 2];
      reps[pos] = make_float4(x, y, z, sumsq_nc(x, y, z));
    }
  }
}

__global__ __launch_bounds__(256) void k_main_fb(const float* __restrict__ q,
                                                 const float4* __restrict__ reps,
                                                 float* __restrict__ part) {
  __shared__ float4 lds[RPC];
  int t = threadIdx.x;
  int c = blockIdx.y;
  const float4* rp = reps + c * RPC;
  if (t < RPC) lds[t] = rp[t];
  int qbase = blockIdx.x * (256 * QPT) + t;
  float qx[QPT], qy[QPT], qz[QPT], mn[QPT];
#pragma unroll
  for (int k = 0; k < QPT; ++k) {
    int i = qbase + k * 256;
    qx[k] = -2.0f * q[3 * i];
    qy[k] = -2.0f * q[3 * i + 1];
    qz[k] = -2.0f * q[3 * i + 2];
    mn[k] = 1e30f;
  }
  __syncthreads();
#pragma unroll 2
  for (int j = 0; j < RPC; j += 4) {
    float4 r0 = lds[j], r1 = lds[j + 1], r2 = lds[j + 2], r3 = lds[j + 3];
#pragma unroll
    for (int k = 0; k < QPT; ++k) {
      float t0 = fmaf(qx[k], r0.x, fmaf(qy[k], r0.y, fmaf(qz[k], r0.z, r0.w)));
      float t1 = fmaf(qx[k], r1.x, fmaf(qy[k], r1.y, fmaf(qz[k], r1.z, r1.w)));
      float t2 = fmaf(qx[k], r2.x, fmaf(qy[k], r2.y, fmaf(qz[k], r2.z, r2.w)));
      float t3 = fmaf(qx[k], r3.x, fmaf(qy[k], r3.y, fmaf(qz[k], r3.z, r3.w)));
      mn[k] = fminf(mn[k], fminf(t0, t1));
      mn[k] = fminf(mn[k], fminf(t2, t3));
    }
  }
#pragma unroll
  for (int k = 0; k < QPT; ++k) part[c * NQ + qbase + k * 256] = mn[k];
}

__global__ __launch_bounds__(256) void k_reduce_fb(const float* __restrict__ q,
                                                   const float* __restrict__ part,
                                                   float* __restrict__ out) {
  int i = blockIdx.x * 256 + threadIdx.x;
  float m = part[i];
#pragma unroll
  for (int c = 1; c < NCH; ++c) m = fminf(m, part[c * NQ + i]);
  float x = q[3 * i], y = q[3 * i + 1], z = q[3 * i + 2];
  float s = sumsq_nc(x, y, z);
  float d = sqrtf(s) - 0.5f;
  float d2 = fmaxf(s + m, 0.0f);
  float nd = (d2 > 0.0f) ? sqrtf(d2) : 0.0f;
  float sg = (d > 0.0f) ? 1.0f : ((d < 0.0f) ? -1.0f : 0.0f);
  out[i] = fminf(nd * sg, d);
}

extern "C" void kernel_launch(void* const* d_in, const int* in_sizes, int n_in,
                              void* d_out, int out_size, void* d_ws, size_t ws_size,
                              hipStream_t stream) {
  const float* q = (const float*)d_in[0];
  float* out = (float*)d_out;
  char* ws = (char*)d_ws;

  unsigned* hist = (unsigned*)(ws + HIST_OFF);
  unsigned* ctrl = (unsigned*)(ws + CTRL_OFF);
  unsigned* keys = (unsigned*)(ws + KEYS_OFF);
  unsigned* cand = (unsigned*)(ws + CAND_OFF);
  float4* reps   = (float4*)(ws + REPS_OFF);
  float* part    = (float*)(ws + PART_OFF);

  // zero hist + ctrl every call (ws is poisoned, never re-poisoned)
  hipMemsetAsync(ws, 0, CTRL_OFF + 256, stream);

  const float* qa = q;
  unsigned* ka = keys; unsigned* ha = hist; unsigned* ca = ctrl;
  unsigned* cda = cand; float4* ra = reps; float* pa = part; float* oa = out;
  void* args[] = {&qa, &ka, &ha, &ca, &cda, &ra, &pa, &oa};
  hipError_t e = hipLaunchCooperativeKernel((void*)k_mega, dim3(NB), dim3(256),
                                            args, 0, stream);
  if (e != hipSuccess) {
    // fallback: proven multi-kernel pipeline (identical math)
    k_keys<<<128, 256, 0, stream>>>(q, keys, hist, ctrl);
    k_compact1<<<128, 256, 0, stream>>>(keys, hist, ctrl, cand);
    k_repbuild<<<128, 256, 0, stream>>>(q, keys, hist, ctrl, cand, reps);
    k_main_fb<<<dim3(NQ / (256 * QPT), NCH), 256, 0, stream>>>(q, reps, part);
    k_reduce_fb<<<NQ / 256, 256, 0, stream>>>(q, part, out);
  }
}

// Round 7
// 62.302 us; speedup vs baseline: 6.4896x; 6.4896x over previous
//
#include <hip/hip_runtime.h>

#define NQ   131072
#define PCNT 2048
#define NBIN 4096

// ws layout (bytes)
#define HIST_OFF 0                         /* NBIN*4 = 16384 */
#define CTRL_OFF 16384                     /* 256 B  */
#define KEYS_OFF (16384 + 256)             /* NQ*4   */
#define CAND_OFF (KEYS_OFF + NQ * 4)       /* NQ*4   */
#define REPS_OFF (CAND_OFF + NQ * 4)       /* PCNT*16, 16B aligned */

// ctrl: [5]=curL [6]=curE [7]=cand cursor (M)

__device__ __forceinline__ float sumsq_nc(float x, float y, float z) {
#pragma clang fp contract(off)
  return x * x + y * y + z * z;
}

// 128 blocks x 256 thr x 4 pts: keys + LDS-aggregated 12-bit histogram
__global__ __launch_bounds__(256) void k_keys(const float* __restrict__ q,
                                              unsigned* __restrict__ keys,
                                              unsigned* __restrict__ hist,
                                              unsigned* __restrict__ ctrl) {
  __shared__ unsigned h[NBIN];
  int t = threadIdx.x;
  for (int j = t; j < NBIN; j += 256) h[j] = 0;
  if (blockIdx.x == 0 && t >= 5 && t < 8) ctrl[t] = 0;
  __syncthreads();
  int base = blockIdx.x * 256 + t;
#pragma unroll
  for (int l = 0; l < 4; ++l) {
    int i = base + l * 32768;
    float x = q[3 * i], y = q[3 * i + 1], z = q[3 * i + 2];
    float s = sumsq_nc(x, y, z);
    float d = sqrtf(s) - 0.5f;
    unsigned k = __float_as_uint(fabsf(d));  // nonneg float: bits monotone
    keys[i] = k;
    atomicAdd(&h[k >> 20], 1u);
  }
  __syncthreads();
  for (int j = t; j < NBIN; j += 256) {
    unsigned v = h[j];
    if (v) atomicAdd(&hist[j], v);
  }
}

// per-block coarse scan: bin B1 containing the PCNT-th smallest, C1 = #below
__device__ __forceinline__ void coarse_scan(const unsigned* __restrict__ hist,
                                            unsigned* part, unsigned* pB1,
                                            unsigned* pC1) {
  int t = threadIdx.x;
  unsigned s = 0;
  for (int j = 0; j < 16; ++j) s += hist[t * 16 + j];
  part[t] = s;
  __syncthreads();
  if (t == 0) {
    unsigned cum = 0; int c = 0;
    for (; c < 256; ++c) { if (cum + part[c] >= PCNT) break; cum += part[c]; }
    unsigned b = c * 16;
    for (;; ++b) { unsigned v = hist[b]; if (cum + v >= PCNT) break; cum += v; }
    *pB1 = b; *pC1 = cum;
  }
  __syncthreads();
}

// 128 blocks x 256 x 4: push keys with top-12 == B1 into cand (values only)
__global__ __launch_bounds__(256) void k_compact1(const unsigned* __restrict__ keys,
                                                  const unsigned* __restrict__ hist,
                                                  unsigned* __restrict__ ctrl,
                                                  unsigned* __restrict__ cand) {
  __shared__ unsigned part[256];
  __shared__ unsigned sB1, sC1;
  __shared__ unsigned tot, base, cur;
  int t = threadIdx.x;
  if (t == 0) tot = 0;
  coarse_scan(hist, part, &sB1, &sC1);
  unsigned B1 = sB1;
  int st = blockIdx.x * 256 + t;
  unsigned kk[4]; unsigned n = 0;
#pragma unroll
  for (int l = 0; l < 4; ++l) { kk[l] = keys[st + l * 32768]; n += ((kk[l] >> 20) == B1); }
  if (n) atomicAdd(&tot, n);
  __syncthreads();
  if (t == 0) { base = atomicAdd(&ctrl[7], tot); cur = 0; }
  __syncthreads();
  int lane = t & 63;
#pragma unroll
  for (int l = 0; l < 4; ++l) {
    bool m = (kk[l] >> 20) == B1;
    unsigned long long mb = __ballot(m);
    unsigned wcnt = __popcll(mb);
    if (wcnt) {
      unsigned lb = 0;
      if (lane == 0) lb = atomicAdd(&cur, wcnt);
      lb = __shfl(lb, 0);
      if (m) cand[base + lb + __popcll(mb & ((1ull << lane) - 1ull))] = kk[l];
    }
  }
}

// 128 blocks x 256 x 4: inline exact select (over cand) + build reps[]
__global__ __launch_bounds__(256) void k_repbuild(const float* __restrict__ q,
                                                  const unsigned* __restrict__ keys,
                                                  const unsigned* __restrict__ hist,
                                                  unsigned* __restrict__ ctrl,
                                                  const unsigned* __restrict__ cand,
                                                  float4* __restrict__ reps) {
  __shared__ unsigned part[256];
  __shared__ unsigned h2[NBIN];
  __shared__ unsigned h3[256];
  __shared__ unsigned sB1, sC1, sB2, sC2, sN2, sT, sCL, sK2;
  __shared__ unsigned totL, totE, curL, curE;
  int t = threadIdx.x;
  for (int j = t; j < NBIN; j += 256) h2[j] = 0;
  h3[t] = 0;
  if (t == 0) { totL = 0; totE = 0; }
  coarse_scan(hist, part, &sB1, &sC1);   // includes syncthreads
  unsigned M = ctrl[7];
  for (unsigned j = t; j < M; j += 256) atomicAdd(&h2[(cand[j] >> 8) & 0xFFFu], 1u);
  __syncthreads();
  unsigned s = 0;
  for (int j = 0; j < 16; ++j) s += h2[t * 16 + j];
  part[t] = s;
  __syncthreads();
  if (t == 0) {
    unsigned need = PCNT - sC1;
    unsigned cum = 0; int c = 0;
    for (; c < 256; ++c) { if (cum + part[c] >= need) break; cum += part[c]; }
    unsigned b = c * 16;
    for (;; ++b) { unsigned v = h2[b]; if (cum + v >= need) break; cum += v; }
    sB2 = b; sC2 = cum; sN2 = need - cum;
  }
  __syncthreads();
  unsigned b2 = sB2;
  for (unsigned j = t; j < M; j += 256) {
    unsigned k = cand[j];
    if (((k >> 8) & 0xFFFu) == b2) atomicAdd(&h3[k & 0xFFu], 1u);
  }
  __syncthreads();
  if (t == 0) {
    unsigned need2 = sN2, cum = 0, b = 0;
    for (;; ++b) { unsigned v = h3[b]; if (cum + v >= need2) break; cum += v; }
    sT = (sB1 << 20) | (b2 << 8) | b;
    sCL = sC1 + sC2 + cum;
    sK2 = PCNT - sCL;
  }
  __syncthreads();
  unsigned T = sT, CL = sCL, K2 = sK2;
  int st = blockIdx.x * 256 + t;
  unsigned kk[4]; unsigned nl = 0, ne = 0;
#pragma unroll
  for (int l = 0; l < 4; ++l) {
    kk[l] = keys[st + l * 32768];
    nl += (kk[l] < T); ne += (kk[l] == T);
  }
  if (nl) atomicAdd(&totL, nl);
  if (ne) atomicAdd(&totE, ne);
  __syncthreads();
  if (t == 0) { curL = atomicAdd(&ctrl[5], totL); curE = atomicAdd(&ctrl[6], totE); }
  __syncthreads();
  int lane = t & 63;
#pragma unroll
  for (int l = 0; l < 4; ++l) {
    int i = st + l * 32768;
    unsigned k = kk[l];
    bool lt = k < T, eq = k == T;
    unsigned long long ml = __ballot(lt), me = __ballot(eq);
    unsigned wl = __popcll(ml), we = __popcll(me);
    unsigned bl = 0, be = 0;
    if (wl) { if (lane == 0) bl = atomicAdd(&curL, wl); bl = __shfl(bl, 0); }
    if (we) { if (lane == 0) be = atomicAdd(&curE, we); be = __shfl(be, 0); }
    int pos = -1;
    if (lt) pos = (int)(bl + __popcll(ml & ((1ull << lane) - 1ull)));
    else if (eq) {
      unsigned e = be + __popcll(me & ((1ull << lane) - 1ull));
      if (e < K2) pos = (int)(CL + e);
    }
    if (pos >= 0) {
      float x = q[3 * i], y = q[3 * i + 1], z = q[3 * i + 2];
      reps[pos] = make_float4(x, y, z, sumsq_nc(x, y, z));
    }
  }
}

// 1024 blocks x 256 thr: 128 queries/block, 8 threads/query (1 per 256-rep
// strided chunk), all 2048 reps in LDS, fused reduce + epilogue.
// Strided chunking (rep j = chunk + 8*jj) -> per-wave the 8 broadcast
// addresses land in 8 disjoint bank quartets: zero LDS conflicts.
__global__ __launch_bounds__(256, 4) void k_main2(const float* __restrict__ q,
                                                  const float4* __restrict__ reps,
                                                  float* __restrict__ out) {
  __shared__ float4 lds[PCNT];  // 32 KB
  int t = threadIdx.x;
  for (int j = t; j < PCNT; j += 256) lds[j] = reps[j];
  int lane = t & 63;
  int wv = t >> 6;
  int chunk = lane >> 3;   // 0..7: which rep residue class
  int qlane = lane & 7;    // 0..7: which query slot
  int qbase = blockIdx.x * 128 + wv * 32 + qlane;
  float qx[4], qy[4], qz[4], ss[4], mn[4];
#pragma unroll
  for (int k = 0; k < 4; ++k) {
    int i = qbase + k * 8;
    float x = q[3 * i], y = q[3 * i + 1], z = q[3 * i + 2];
    ss[k] = sumsq_nc(x, y, z);
    qx[k] = -2.0f * x; qy[k] = -2.0f * y; qz[k] = -2.0f * z;
    mn[k] = 1e30f;
  }
  __syncthreads();
#pragma unroll 2
  for (int jj = 0; jj < 256; jj += 4) {
    float4 r0 = lds[chunk + 8 * jj];
    float4 r1 = lds[chunk + 8 * jj + 8];
    float4 r2 = lds[chunk + 8 * jj + 16];
    float4 r3 = lds[chunk + 8 * jj + 24];
#pragma unroll
    for (int k = 0; k < 4; ++k) {
      float t0 = fmaf(qx[k], r0.x, fmaf(qy[k], r0.y, fmaf(qz[k], r0.z, r0.w)));
      float t1 = fmaf(qx[k], r1.x, fmaf(qy[k], r1.y, fmaf(qz[k], r1.z, r1.w)));
      float t2 = fmaf(qx[k], r2.x, fmaf(qy[k], r2.y, fmaf(qz[k], r2.z, r2.w)));
      float t3 = fmaf(qx[k], r3.x, fmaf(qy[k], r3.y, fmaf(qz[k], r3.z, r3.w)));
      mn[k] = fminf(mn[k], fminf(t0, t1));  // v_min3_f32
      mn[k] = fminf(mn[k], fminf(t2, t3));
    }
  }
#pragma unroll
  for (int k = 0; k < 4; ++k) {
    mn[k] = fminf(mn[k], __shfl_xor(mn[k], 8));
    mn[k] = fminf(mn[k], __shfl_xor(mn[k], 16));
    mn[k] = fminf(mn[k], __shfl_xor(mn[k], 32));
  }
  if (chunk == 0) {
#pragma unroll
    for (int k = 0; k < 4; ++k) {
      int i = qbase + k * 8;
      float s = ss[k];
      float d = sqrtf(s) - 0.5f;
      float d2 = fmaxf(s + mn[k], 0.0f);
      float nd = (d2 > 0.0f) ? sqrtf(d2) : 0.0f;
      float sg = (d > 0.0f) ? 1.0f : ((d < 0.0f) ? -1.0f : 0.0f);
      out[i] = fminf(nd * sg, d);
    }
  }
}

extern "C" void kernel_launch(void* const* d_in, const int* in_sizes, int n_in,
                              void* d_out, int out_size, void* d_ws, size_t ws_size,
                              hipStream_t stream) {
  const float* q = (const float*)d_in[0];
  float* out = (float*)d_out;
  char* ws = (char*)d_ws;

  unsigned* hist = (unsigned*)(ws + HIST_OFF);
  unsigned* ctrl = (unsigned*)(ws + CTRL_OFF);
  unsigned* keys = (unsigned*)(ws + KEYS_OFF);
  unsigned* cand = (unsigned*)(ws + CAND_OFF);
  float4* reps   = (float4*)(ws + REPS_OFF);

  hipMemsetAsync(hist, 0, NBIN * 4, stream);
  k_keys<<<128, 256, 0, stream>>>(q, keys, hist, ctrl);
  k_compact1<<<128, 256, 0, stream>>>(keys, hist, ctrl, cand);
  k_repbuild<<<128, 256, 0, stream>>>(q, keys, hist, ctrl, cand, reps);
  k_main2<<<NQ / 128, 256, 0, stream>>>(q, reps, out);
}

// Round 8
// 56.749 us; speedup vs baseline: 7.1246x; 1.0978x over previous
//
#include <hip/hip_runtime.h>

#define NQ   131072
#define PCNT 2048
#define NBIN 4096

// ws layout (bytes)
#define HIST_OFF  0                           /* hist 16KB + h2 16KB */
#define CTRL_OFF  (2 * NBIN * 4)              /* 32768, 256 B */
#define KEYS_OFF  (CTRL_OFF + 256)            /* NQ*4, 16B aligned */
#define CANDK_OFF (KEYS_OFF + NQ * 4)         /* NQ*4 */
#define CANDI_OFF (CANDK_OFF + NQ * 4)        /* NQ*4 */

// ctrl: [0]=B1 [1]=C1 [7]=cand count

__device__ __forceinline__ float sumsq_nc(float x, float y, float z) {
#pragma clang fp contract(off)
  return x * x + y * y + z * z;
}

// parallel "which thread's partial contains the need-th element" find.
// Each thread contributes mycnt; publishes selected thread id + cum-below.
__device__ __forceinline__ void pfind256(unsigned mycnt, unsigned need,
                                         unsigned* wsum, unsigned* sel,
                                         unsigned* cum) {
  int t = threadIdx.x, lane = t & 63, wv = t >> 6;
  unsigned p = mycnt;
#pragma unroll
  for (int d = 1; d < 64; d <<= 1) {
    unsigned v = __shfl_up(p, d);
    if (lane >= d) p += v;
  }
  if (lane == 63) wsum[wv] = p;
  __syncthreads();
  unsigned base = 0;
  for (int w = 0; w < wv; ++w) base += wsum[w];
  unsigned pincl = p + base, pexcl = pincl - mycnt;
  if (pexcl < need && pincl >= need) { *sel = (unsigned)t; *cum = pexcl; }
  __syncthreads();
}

// 128 blocks x 256 thr x 4 consecutive pts: keys (uint4) + LDS 12-bit hist
__global__ __launch_bounds__(256) void k_keys(const float4* __restrict__ q4,
                                              uint4* __restrict__ keys4,
                                              unsigned* __restrict__ hist,
                                              unsigned* __restrict__ ctrl) {
  __shared__ unsigned h[NBIN];
  int t = threadIdx.x;
  for (int j = t; j < NBIN; j += 256) h[j] = 0;
  if (blockIdx.x == 0 && t < 8) ctrl[t] = 0;
  __syncthreads();
  int gid = blockIdx.x * 256 + t;
  int b = 3 * gid;
  float4 A = q4[b], B = q4[b + 1], C = q4[b + 2];
  float xs[4] = {A.x, A.w, B.z, C.y};
  float ys[4] = {A.y, B.x, B.w, C.z};
  float zs[4] = {A.z, B.y, C.x, C.w};
  unsigned kk[4];
#pragma unroll
  for (int l = 0; l < 4; ++l) {
    float s = sumsq_nc(xs[l], ys[l], zs[l]);
    float d = sqrtf(s) - 0.5f;
    kk[l] = __float_as_uint(fabsf(d));  // nonneg float: bits monotone
    atomicAdd(&h[kk[l] >> 20], 1u);
  }
  keys4[gid] = make_uint4(kk[0], kk[1], kk[2], kk[3]);
  __syncthreads();
  for (int j = t; j < NBIN; j += 256) {
    unsigned v = h[j];
    if (v) atomicAdd(&hist[j], v);
  }
}

// 128 blocks x 256 x 4: find B1; emit (key,idx) for top12<=B1; count C1;
// build global h2 (mid-12 bits) for the boundary bin
__global__ __launch_bounds__(256) void k_compact(const uint4* __restrict__ keys4,
                                                 const unsigned* __restrict__ hist,
                                                 unsigned* __restrict__ h2,
                                                 unsigned* __restrict__ ctrl,
                                                 unsigned* __restrict__ candk,
                                                 unsigned* __restrict__ candi) {
  __shared__ unsigned wsum[4];
  __shared__ unsigned sSel, sCum, sB1;
  __shared__ unsigned totC, totL, base, cur;
  int t = threadIdx.x;
  if (t == 0) { totC = 0; totL = 0; }
  const uint4* h4 = (const uint4*)hist;
  uint4 H0 = h4[4 * t], H1 = h4[4 * t + 1], H2v = h4[4 * t + 2], H3 = h4[4 * t + 3];
  unsigned r[16] = {H0.x, H0.y, H0.z, H0.w, H1.x, H1.y, H1.z, H1.w,
                    H2v.x, H2v.y, H2v.z, H2v.w, H3.x, H3.y, H3.z, H3.w};
  unsigned mycnt = 0;
#pragma unroll
  for (int j = 0; j < 16; ++j) mycnt += r[j];
  pfind256(mycnt, PCNT, wsum, &sSel, &sCum);
  if (t == (int)sSel) {
    unsigned cc = sCum; int found = -1;
#pragma unroll
    for (int j = 0; j < 16; ++j) {
      if (found < 0) { if (cc + r[j] >= PCNT) found = j; else cc += r[j]; }
    }
    sB1 = (unsigned)(t * 16 + found);
  }
  __syncthreads();
  unsigned B1 = sB1;
  if (blockIdx.x == 0 && t == 0) ctrl[0] = B1;
  int gid = blockIdx.x * 256 + t;
  uint4 kv = keys4[gid];
  unsigned ka[4] = {kv.x, kv.y, kv.z, kv.w};
  unsigned nM = 0, nL = 0;
#pragma unroll
  for (int l = 0; l < 4; ++l) {
    unsigned hb = ka[l] >> 20;
    nM += (hb <= B1); nL += (hb < B1);
  }
  if (nM) atomicAdd(&totC, nM);
  if (nL) atomicAdd(&totL, nL);
  __syncthreads();
  if (t == 0) {
    base = atomicAdd(&ctrl[7], totC);
    if (totL) atomicAdd(&ctrl[1], totL);
    cur = 0;
  }
  __syncthreads();
  int lane = t & 63;
#pragma unroll
  for (int l = 0; l < 4; ++l) {
    unsigned k = ka[l];
    bool m = (k >> 20) <= B1;
    unsigned long long mb = __ballot(m);
    unsigned wcnt = __popcll(mb);
    if (wcnt) {
      unsigned lb = 0;
      if (lane == 0) lb = atomicAdd(&cur, wcnt);
      lb = __shfl(lb, 0);
      if (m) {
        unsigned pos = base + lb + __popcll(mb & ((1ull << lane) - 1ull));
        candk[pos] = k;
        candi[pos] = (unsigned)(4 * gid + l);
        if ((k >> 20) == B1) atomicAdd(&h2[(k >> 8) & 0xFFFu], 1u);
      }
    }
  }
}

// 1024 blocks x 256: per-block redundant exact select over cand (tiny,
// L2-resident) -> build 2048 reps directly in LDS -> distance loop ->
// fused reduce + epilogue. 128 queries/block, 8 lanes/query.
__global__ __launch_bounds__(256, 4) void k_main3(const float* __restrict__ q,
                                                  const unsigned* __restrict__ candk,
                                                  const unsigned* __restrict__ candi,
                                                  const unsigned* __restrict__ ctrl,
                                                  const unsigned* __restrict__ h2,
                                                  float* __restrict__ out) {
  __shared__ __align__(16) float4 repl[PCNT];  // 32 KB; first 1KB doubles as histC
  __shared__ unsigned wsum[4];
  __shared__ unsigned sSel, sCum, sB2, sCumB, sT, sCL, sK2, sCurL, sCurE;
  unsigned* histC = (unsigned*)repl;
  int t = threadIdx.x;
  unsigned N = ctrl[7], B1 = ctrl[0], C1 = ctrl[1];
  unsigned needB = PCNT - C1;
  int lane = t & 63, wv = t >> 6;
  int chunk = lane >> 3;   // 0..7: rep residue class
  int qlane = lane & 7;    // 0..7: query slot
  int qbase = blockIdx.x * 128 + wv * 32 + qlane;
  float qx[4], qy[4], qz[4], ss[4], mn[4];
#pragma unroll
  for (int k = 0; k < 4; ++k) {
    int i = qbase + k * 8;
    float x = q[3 * i], y = q[3 * i + 1], z = q[3 * i + 2];
    ss[k] = sumsq_nc(x, y, z);
    qx[k] = -2.0f * x; qy[k] = -2.0f * y; qz[k] = -2.0f * z;
    mn[k] = 1e30f;
  }
  // P0: find B2 from global h2 (no stream over cand needed)
  {
    const uint4* h24 = (const uint4*)h2;
    uint4 H0 = h24[4 * t], H1 = h24[4 * t + 1], H2v = h24[4 * t + 2], H3 = h24[4 * t + 3];
    unsigned r[16] = {H0.x, H0.y, H0.z, H0.w, H1.x, H1.y, H1.z, H1.w,
                      H2v.x, H2v.y, H2v.z, H2v.w, H3.x, H3.y, H3.z, H3.w};
    unsigned mycnt = 0;
#pragma unroll
    for (int j = 0; j < 16; ++j) mycnt += r[j];
    pfind256(mycnt, needB, wsum, &sSel, &sCum);
    if (t == (int)sSel) {
      unsigned cc = sCum; int found = -1;
#pragma unroll
      for (int j = 0; j < 16; ++j) {
        if (found < 0) { if (cc + r[j] >= needB) found = j; else cc += r[j]; }
      }
      sB2 = (unsigned)(t * 16 + found); sCumB = cc;
    }
  }
  histC[t] = 0;
  __syncthreads();
  unsigned B2 = sB2, cumB = sCumB, needC = needB - cumB;
  unsigned tgt = (B1 << 12) | B2;
  // P1: low-8 histogram of boundary-(B1,B2) candidates
  for (unsigned jb = 0; jb < N; jb += 256) {
    unsigned j = jb + t;
    if (j < N) {
      unsigned k = candk[j];
      if ((k >> 8) == tgt) atomicAdd(&histC[k & 0xFFu], 1u);
    }
  }
  __syncthreads();
  unsigned cbin = histC[t];
  pfind256(cbin, needC, wsum, &sSel, &sCum);
  if (t == (int)sSel) {
    unsigned CLv = C1 + cumB + sCum;
    sT = (B1 << 20) | (B2 << 8) | (unsigned)t;
    sCL = CLv;
    sK2 = PCNT - CLv;
  }
  if (t == 0) { sCurL = 0; sCurE = 0; }
  __syncthreads();
  unsigned T = sT, CL = sCL, K2 = sK2;
  // P2: gather selected reps into LDS (order-free; min is order-independent)
  for (unsigned jb = 0; jb < N; jb += 256) {
    unsigned j = jb + t;
    unsigned k = (j < N) ? candk[j] : 0xFFFFFFFFu;
    bool lt = k < T, eq = (k == T);
    unsigned long long ml = __ballot(lt), me = __ballot(eq);
    unsigned wl = __popcll(ml), we = __popcll(me);
    unsigned bl = 0, be = 0;
    if (wl) { if (lane == 0) bl = atomicAdd(&sCurL, wl); bl = __shfl(bl, 0); }
    if (we) { if (lane == 0) be = atomicAdd(&sCurE, we); be = __shfl(be, 0); }
    int pos = -1;
    if (lt) pos = (int)(bl + __popcll(ml & ((1ull << lane) - 1ull)));
    else if (eq) {
      unsigned e = be + __popcll(me & ((1ull << lane) - 1ull));
      if (e < K2) pos = (int)(CL + e);
    }
    if (pos >= 0) {
      unsigned i = candi[j];
      float x = q[3 * i], y = q[3 * i + 1], z = q[3 * i + 2];
      repl[pos] = make_float4(x, y, z, sumsq_nc(x, y, z));
    }
  }
  __syncthreads();
  // P3: distance loop (strided chunks -> conflict-free broadcast)
#pragma unroll 2
  for (int jj = 0; jj < 256; jj += 4) {
    float4 r0 = repl[chunk + 8 * jj];
    float4 r1 = repl[chunk + 8 * jj + 8];
    float4 r2 = repl[chunk + 8 * jj + 16];
    float4 r3 = repl[chunk + 8 * jj + 24];
#pragma unroll
    for (int k = 0; k < 4; ++k) {
      float t0 = fmaf(qx[k], r0.x, fmaf(qy[k], r0.y, fmaf(qz[k], r0.z, r0.w)));
      float t1 = fmaf(qx[k], r1.x, fmaf(qy[k], r1.y, fmaf(qz[k], r1.z, r1.w)));
      float t2 = fmaf(qx[k], r2.x, fmaf(qy[k], r2.y, fmaf(qz[k], r2.z, r2.w)));
      float t3 = fmaf(qx[k], r3.x, fmaf(qy[k], r3.y, fmaf(qz[k], r3.z, r3.w)));
      mn[k] = fminf(mn[k], fminf(t0, t1));  // v_min3_f32
      mn[k] = fminf(mn[k], fminf(t2, t3));
    }
  }
#pragma unroll
  for (int k = 0; k < 4; ++k) {
    mn[k] = fminf(mn[k], __shfl_xor(mn[k], 8));
    mn[k] = fminf(mn[k], __shfl_xor(mn[k], 16));
    mn[k] = fminf(mn[k], __shfl_xor(mn[k], 32));
  }
  if (chunk == 0) {
#pragma unroll
    for (int k = 0; k < 4; ++k) {
      int i = qbase + k * 8;
      float s = ss[k];
      float d = sqrtf(s) - 0.5f;
      float d2 = fmaxf(s + mn[k], 0.0f);
      float nd = (d2 > 0.0f) ? sqrtf(d2) : 0.0f;
      float sg = (d > 0.0f) ? 1.0f : ((d < 0.0f) ? -1.0f : 0.0f);
      out[i] = fminf(nd * sg, d);
    }
  }
}

extern "C" void kernel_launch(void* const* d_in, const int* in_sizes, int n_in,
                              void* d_out, int out_size, void* d_ws, size_t ws_size,
                              hipStream_t stream) {
  const float* q = (const float*)d_in[0];
  float* out = (float*)d_out;
  char* ws = (char*)d_ws;

  unsigned* hist  = (unsigned*)(ws + HIST_OFF);
  unsigned* h2    = hist + NBIN;
  unsigned* ctrl  = (unsigned*)(ws + CTRL_OFF);
  uint4*    keys4 = (uint4*)(ws + KEYS_OFF);
  unsigned* candk = (unsigned*)(ws + CANDK_OFF);
  unsigned* candi = (unsigned*)(ws + CANDI_OFF);

  hipMemsetAsync(hist, 0, 2 * NBIN * 4, stream);
  k_keys<<<128, 256, 0, stream>>>((const float4*)q, keys4, hist, ctrl);
  k_compact<<<128, 256, 0, stream>>>(keys4, hist, h2, ctrl, candk, candi);
  k_main3<<<NQ / 128, 256, 0, stream>>>(q, candk, candi, ctrl, h2, out);
}

// Round 9
// 56.563 us; speedup vs baseline: 7.1480x; 1.0033x over previous
//
#include <hip/hip_runtime.h>

#define NQ   131072
#define PCNT 2048
#define NBIN 4096

typedef __attribute__((ext_vector_type(8))) short short8v;
typedef __attribute__((ext_vector_type(4))) float f32x4;

// ws layout (bytes)
#define HIST_OFF  0                           /* 16 KB */
#define H2_OFF    (NBIN * 4)                  /* 16 KB */
#define CTRL_OFF  (2 * NBIN * 4)              /* 32768, 256 B */
#define KEYS_OFF  (CTRL_OFF + 256)            /* NQ*4, 16B aligned */
#define CANDK_OFF (KEYS_OFF + NQ * 4)
#define CANDI_OFF (CANDK_OFF + NQ * 4)
#define REPP_OFF  (CANDI_OFF + NQ * 4)        /* PCNT*16 packed frags */

// ctrl: [0]=B1 [1]=C1 [5]=curL [6]=curE [7]=cand count

__device__ __forceinline__ float sumsq_nc(float x, float y, float z) {
#pragma clang fp contract(off)
  return x * x + y * y + z * z;
}

__device__ __forceinline__ unsigned short bf_rne(float f) {
  unsigned u = __float_as_uint(f);
  return (unsigned short)((u + 0x7FFFu + ((u >> 16) & 1u)) >> 16);
}
__device__ __forceinline__ float bf2f(unsigned short h) {
  return __uint_as_float(((unsigned)h) << 16);
}
__device__ __forceinline__ unsigned fsort(float f) {
  unsigned u = __float_as_uint(f);
  return (u & 0x80000000u) ? ~u : (u | 0x80000000u);
}
__device__ __forceinline__ float funsort(unsigned u) {
  unsigned v = (u & 0x80000000u) ? (u ^ 0x80000000u) : ~u;
  return __uint_as_float(v);
}

// parallel "which thread's partial contains the need-th element" find
__device__ __forceinline__ void pfind256(unsigned mycnt, unsigned need,
                                         unsigned* wsum, unsigned* sel,
                                         unsigned* cum) {
  int t = threadIdx.x, lane = t & 63, wv = t >> 6;
  unsigned p = mycnt;
#pragma unroll
  for (int d = 1; d < 64; d <<= 1) {
    unsigned v = __shfl_up(p, d);
    if (lane >= d) p += v;
  }
  if (lane == 63) wsum[wv] = p;
  __syncthreads();
  unsigned base = 0;
  for (int w = 0; w < wv; ++w) base += wsum[w];
  unsigned pincl = p + base, pexcl = pincl - mycnt;
  if (pexcl < need && pincl >= need) { *sel = (unsigned)t; *cum = pexcl; }
  __syncthreads();
}

// 128 blocks x 256 x 4: keys + LDS 12-bit hist
__global__ __launch_bounds__(256) void k_keys(const float4* __restrict__ q4,
                                              uint4* __restrict__ keys4,
                                              unsigned* __restrict__ hist,
                                              unsigned* __restrict__ ctrl) {
  __shared__ unsigned h[NBIN];
  int t = threadIdx.x;
  for (int j = t; j < NBIN; j += 256) h[j] = 0;
  if (blockIdx.x == 0 && t < 8) ctrl[t] = 0;
  __syncthreads();
  int gid = blockIdx.x * 256 + t;
  int b = 3 * gid;
  float4 A = q4[b], B = q4[b + 1], C = q4[b + 2];
  float xs[4] = {A.x, A.w, B.z, C.y};
  float ys[4] = {A.y, B.x, B.w, C.z};
  float zs[4] = {A.z, B.y, C.x, C.w};
  unsigned kk[4];
#pragma unroll
  for (int l = 0; l < 4; ++l) {
    float s = sumsq_nc(xs[l], ys[l], zs[l]);
    float d = sqrtf(s) - 0.5f;
    kk[l] = __float_as_uint(fabsf(d));
    atomicAdd(&h[kk[l] >> 20], 1u);
  }
  keys4[gid] = make_uint4(kk[0], kk[1], kk[2], kk[3]);
  __syncthreads();
  for (int j = t; j < NBIN; j += 256) {
    unsigned v = h[j];
    if (v) atomicAdd(&hist[j], v);
  }
}

// 128 blocks x 256 x 4: find B1; emit (key,idx) for top12<=B1; C1; h2 of B1
__global__ __launch_bounds__(256) void k_compact(const uint4* __restrict__ keys4,
                                                 const unsigned* __restrict__ hist,
                                                 unsigned* __restrict__ h2,
                                                 unsigned* __restrict__ ctrl,
                                                 unsigned* __restrict__ candk,
                                                 unsigned* __restrict__ candi) {
  __shared__ unsigned wsum[4];
  __shared__ unsigned sSel, sCum, sB1;
  __shared__ unsigned totC, totL, base, cur;
  int t = threadIdx.x;
  if (t == 0) { totC = 0; totL = 0; }
  const uint4* h4 = (const uint4*)hist;
  uint4 H0 = h4[4 * t], H1 = h4[4 * t + 1], H2v = h4[4 * t + 2], H3 = h4[4 * t + 3];
  unsigned r[16] = {H0.x, H0.y, H0.z, H0.w, H1.x, H1.y, H1.z, H1.w,
                    H2v.x, H2v.y, H2v.z, H2v.w, H3.x, H3.y, H3.z, H3.w};
  unsigned mycnt = 0;
#pragma unroll
  for (int j = 0; j < 16; ++j) mycnt += r[j];
  pfind256(mycnt, PCNT, wsum, &sSel, &sCum);
  if (t == (int)sSel) {
    unsigned cc = sCum; int found = -1;
#pragma unroll
    for (int j = 0; j < 16; ++j) {
      if (found < 0) { if (cc + r[j] >= PCNT) found = j; else cc += r[j]; }
    }
    sB1 = (unsigned)(t * 16 + found);
  }
  __syncthreads();
  unsigned B1 = sB1;
  if (blockIdx.x == 0 && t == 0) ctrl[0] = B1;
  int gid = blockIdx.x * 256 + t;
  uint4 kv = keys4[gid];
  unsigned ka[4] = {kv.x, kv.y, kv.z, kv.w};
  unsigned nM = 0, nL = 0;
#pragma unroll
  for (int l = 0; l < 4; ++l) {
    unsigned hb = ka[l] >> 20;
    nM += (hb <= B1); nL += (hb < B1);
  }
  if (nM) atomicAdd(&totC, nM);
  if (nL) atomicAdd(&totL, nL);
  __syncthreads();
  if (t == 0) {
    base = atomicAdd(&ctrl[7], totC);
    if (totL) atomicAdd(&ctrl[1], totL);
    cur = 0;
  }
  __syncthreads();
  int lane = t & 63;
#pragma unroll
  for (int l = 0; l < 4; ++l) {
    unsigned k = ka[l];
    bool m = (k >> 20) <= B1;
    unsigned long long mb = __ballot(m);
    unsigned wcnt = __popcll(mb);
    if (wcnt) {
      unsigned lb = 0;
      if (lane == 0) lb = atomicAdd(&cur, wcnt);
      lb = __shfl(lb, 0);
      if (m) {
        unsigned pos = base + lb + __popcll(mb & ((1ull << lane) - 1ull));
        candk[pos] = k;
        candi[pos] = (unsigned)(4 * gid + l);
        if ((k >> 20) == B1) atomicAdd(&h2[(k >> 8) & 0xFFFu], 1u);
      }
    }
  }
}

// 32 blocks x 256: exact select (redundant per block) + pack selected reps as
// MFMA A-fragments: [r2h, r2l, -2rh0..2, -2rl0..2] as 8 bf16 in one uint4
__global__ __launch_bounds__(256) void k_prep(const float* __restrict__ q,
                                              const unsigned* __restrict__ candk,
                                              const unsigned* __restrict__ candi,
                                              unsigned* __restrict__ ctrl,
                                              const unsigned* __restrict__ h2,
                                              uint4* __restrict__ repp) {
  __shared__ unsigned histC[256];
  __shared__ unsigned wsum[4];
  __shared__ unsigned sSel, sCum, sB2, sCumB, sT, sCL, sK2;
  int t = threadIdx.x, lane = t & 63;
  unsigned N = ctrl[7], B1 = ctrl[0], C1 = ctrl[1];
  unsigned needB = PCNT - C1;
  {
    const uint4* h24 = (const uint4*)h2;
    uint4 H0 = h24[4 * t], H1 = h24[4 * t + 1], H2v = h24[4 * t + 2], H3 = h24[4 * t + 3];
    unsigned r[16] = {H0.x, H0.y, H0.z, H0.w, H1.x, H1.y, H1.z, H1.w,
                      H2v.x, H2v.y, H2v.z, H2v.w, H3.x, H3.y, H3.z, H3.w};
    unsigned mycnt = 0;
#pragma unroll
    for (int j = 0; j < 16; ++j) mycnt += r[j];
    pfind256(mycnt, needB, wsum, &sSel, &sCum);
    if (t == (int)sSel) {
      unsigned cc = sCum; int found = -1;
#pragma unroll
      for (int j = 0; j < 16; ++j) {
        if (found < 0) { if (cc + r[j] >= needB) found = j; else cc += r[j]; }
      }
      sB2 = (unsigned)(t * 16 + found); sCumB = cc;
    }
  }
  histC[t] = 0;
  __syncthreads();
  unsigned B2 = sB2, cumB = sCumB, needC = needB - cumB;
  unsigned tgt = (B1 << 12) | B2;
  for (unsigned jb = 0; jb < N; jb += 256) {
    unsigned j = jb + t;
    if (j < N) {
      unsigned k = candk[j];
      if ((k >> 8) == tgt) atomicAdd(&histC[k & 0xFFu], 1u);
    }
  }
  __syncthreads();
  unsigned cbin = histC[t];
  pfind256(cbin, needC, wsum, &sSel, &sCum);
  if (t == (int)sSel) {
    unsigned CLv = C1 + cumB + sCum;
    sT = (B1 << 20) | (B2 << 8) | (unsigned)t;
    sCL = CLv; sK2 = PCNT - CLv;
  }
  __syncthreads();
  unsigned T = sT, CL = sCL, K2 = sK2;
  // slice of cand per block; global cursors for positions
  unsigned S = (N + 31) / 32;
  unsigned jlo = blockIdx.x * S, jhi = min(N, jlo + S);
  for (unsigned jb = jlo; jb < jhi; jb += 256) {
    unsigned j = jb + t;
    unsigned k = (j < jhi) ? candk[j] : 0xFFFFFFFFu;
    bool lt = k < T, eq = (k == T);
    unsigned long long ml = __ballot(lt), me = __ballot(eq);
    unsigned wl = __popcll(ml), we = __popcll(me);
    unsigned bl = 0, be = 0;
    if (wl) { if (lane == 0) bl = atomicAdd(&ctrl[5], wl); bl = __shfl(bl, 0); }
    if (we) { if (lane == 0) be = atomicAdd(&ctrl[6], we); be = __shfl(be, 0); }
    int pos = -1;
    if (lt) pos = (int)(bl + __popcll(ml & ((1ull << lane) - 1ull)));
    else if (eq) {
      unsigned e = be + __popcll(me & ((1ull << lane) - 1ull));
      if (e < K2) pos = (int)(CL + e);
    }
    if (pos >= 0) {
      unsigned i = candi[j];
      float x = q[3 * i], y = q[3 * i + 1], z = q[3 * i + 2];
      float r2 = sumsq_nc(x, y, z);
      unsigned short r2h = bf_rne(r2);
      unsigned short r2l = bf_rne(r2 - bf2f(r2h));
      float cx = -2.0f * x, cy = -2.0f * y, cz = -2.0f * z;
      unsigned short hx = bf_rne(cx), hy = bf_rne(cy), hz = bf_rne(cz);
      unsigned short lx = bf_rne(cx - bf2f(hx));
      unsigned short ly = bf_rne(cy - bf2f(hy));
      unsigned short lz = bf_rne(cz - bf2f(hz));
      repp[pos] = make_uint4((unsigned)r2h | ((unsigned)r2l << 16),
                             (unsigned)hx | ((unsigned)hy << 16),
                             (unsigned)hz | ((unsigned)lx << 16),
                             (unsigned)ly | ((unsigned)lz << 16));
    }
  }
}

union frag_cast { uint4 u; short8v s; };

// 512 blocks x 256 (4 waves): each wave holds a 512-rep chunk as A-fragments
// in registers (32 tiles x 4 VGPR); block covers 256 queries (16 q-tiles).
// t[rep][query] = r2 - 2 q.r via one mfma_f32_16x16x32_bf16 per 16x16 tile
// (hi/lo bf16 split, slots k0..13). Waves combine via LDS atomicMin.
__global__ __launch_bounds__(256) void k_mfma(const float* __restrict__ q,
                                              const uint4* __restrict__ repp,
                                              float* __restrict__ out) {
  __shared__ unsigned mnq[256];
  int t = threadIdx.x, lane = t & 63, w = t >> 6;
  int g = lane >> 4, ql = lane & 15;
  mnq[t] = 0xFFFFFFFFu;
  // load this wave's 32 rep-tiles; lanes in group g==1 use the dword-shifted
  // frag (k8-15 slots); groups 2,3 multiply zero B-frags so content is moot
  uint4 raw[32];
  const uint4* rp = repp + w * 512;
#pragma unroll
  for (int j = 0; j < 32; ++j) raw[j] = rp[j * 16 + ql];
  bool gs = (g == 1);
#pragma unroll
  for (int j = 0; j < 32; ++j) {
    uint4 v = raw[j];
    raw[j] = gs ? make_uint4(v.y, v.z, v.w, 0u) : v;
  }
  __syncthreads();
  int qbase = blockIdx.x * 256;
  const unsigned one2 = 0x3F803F80u;  // (1.0bf16, 1.0bf16)
  f32x4 zero4 = {0.f, 0.f, 0.f, 0.f};
  for (int qt = 0; qt < 16; ++qt) {
    int qi = qbase + qt * 16 + ql;
    float x = q[3 * qi], y = q[3 * qi + 1], z = q[3 * qi + 2];
    unsigned short hx = bf_rne(x), hy = bf_rne(y), hz = bf_rne(z);
    unsigned short lx = bf_rne(x - bf2f(hx));
    unsigned short ly = bf_rne(y - bf2f(hy));
    unsigned short lz = bf_rne(z - bf2f(hz));
    // B slots k0-7 (g0): [1,1,qh0,qh1,qh2,qh0,qh1,qh2]
    // B slots k8-15 (g1): [ql0,ql1,ql2,ql0,ql1,ql2,0,0] ; g2,g3: zeros
    uint4 bu;
    if (g == 0) {
      bu = make_uint4(one2,
                      (unsigned)hx | ((unsigned)hy << 16),
                      (unsigned)hz | ((unsigned)hx << 16),
                      (unsigned)hy | ((unsigned)hz << 16));
    } else if (g == 1) {
      bu = make_uint4((unsigned)lx | ((unsigned)ly << 16),
                      (unsigned)lz | ((unsigned)lx << 16),
                      (unsigned)ly | ((unsigned)lz << 16), 0u);
    } else {
      bu = make_uint4(0u, 0u, 0u, 0u);
    }
    frag_cast bf; bf.u = bu;
    float mn = 1e30f;
#pragma unroll
    for (int j = 0; j < 32; ++j) {
      frag_cast af; af.u = raw[j];
      f32x4 d = __builtin_amdgcn_mfma_f32_16x16x32_bf16(af.s, bf.s, zero4, 0, 0, 0);
      mn = fminf(mn, fminf(fminf(d[0], d[1]), fminf(d[2], d[3])));
    }
    mn = fminf(mn, __shfl_xor(mn, 16));
    mn = fminf(mn, __shfl_xor(mn, 32));
    if (g == 0) atomicMin(&mnq[qt * 16 + ql], fsort(mn));
  }
  __syncthreads();
  // epilogue: thread t <-> query qbase + t
  int i = qbase + t;
  float tmin = funsort(mnq[t]);
  float x = q[3 * i], y = q[3 * i + 1], z = q[3 * i + 2];
  float s = sumsq_nc(x, y, z);
  float d = sqrtf(s) - 0.5f;
  float d2 = fmaxf(s + tmin, 0.0f);
  float nd = (d2 > 0.0f) ? sqrtf(d2) : 0.0f;
  float sg = (d > 0.0f) ? 1.0f : ((d < 0.0f) ? -1.0f : 0.0f);
  out[i] = fminf(nd * sg, d);
}

extern "C" void kernel_launch(void* const* d_in, const int* in_sizes, int n_in,
                              void* d_out, int out_size, void* d_ws, size_t ws_size,
                              hipStream_t stream) {
  const float* q = (const float*)d_in[0];
  float* out = (float*)d_out;
  char* ws = (char*)d_ws;

  unsigned* hist  = (unsigned*)(ws + HIST_OFF);
  unsigned* h2    = (unsigned*)(ws + H2_OFF);
  unsigned* ctrl  = (unsigned*)(ws + CTRL_OFF);
  uint4*    keys4 = (uint4*)(ws + KEYS_OFF);
  unsigned* candk = (unsigned*)(ws + CANDK_OFF);
  unsigned* candi = (unsigned*)(ws + CANDI_OFF);
  uint4*    repp  = (uint4*)(ws + REPP_OFF);

  hipMemsetAsync(hist, 0, 2 * NBIN * 4, stream);
  k_keys<<<128, 256, 0, stream>>>((const float4*)q, keys4, hist, ctrl);
  k_compact<<<128, 256, 0, stream>>>(keys4, hist, h2, ctrl, candk, candi);
  k_prep<<<32, 256, 0, stream>>>(q, candk, candi, ctrl, h2, repp);
  k_mfma<<<NQ / 256, 256, 0, stream>>>(q, repp, out);
}